// Round 7
// baseline (73.060 us; speedup 1.0000x reference)
//
#include <hip/hip_runtime.h>
#include <math.h>

#define BB 1024
#define NN 128
#define DD 128

__device__ __forceinline__ float sigmoidf_(float x) { return 1.0f / (1.0f + expf(-x)); }

// ---------------------------------------------------------------------------
// k_prep2: blocks 0..63 build Wfull[512][256] = [W_ih[:,:128]+W_hh | W_ih[:,128:]].
// blocks 64..67: gbase[512] = b_ih+b_hh + (W_ih[:,:128]+W_hh)·h1, h1 from biases.
// ---------------------------------------------------------------------------
__global__ __launch_bounds__(256) void k_prep2(
    const float* __restrict__ W_ih, const float* __restrict__ W_hh,
    const float* __restrict__ b_ih, const float* __restrict__ b_hh,
    float* __restrict__ Wfull, float* __restrict__ gbase) {
  int b = blockIdx.x, t = threadIdx.x;
  if (b < 64) {
    int base = b * 2048;                  // 8 rows x 256 cols per block
    for (int i = t; i < 2048; i += 256) {
      int idx = base + i;
      int j = idx >> 8, d = idx & 255;
      float v = W_ih[(j << 8) + d];
      if (d < 128) v += W_hh[(j << 7) + d];
      Wfull[idx] = v;
    }
  } else {
    __shared__ float h1l[DD];
    if (t < DD) {
      float bi = b_ih[t] + b_hh[t];
      float bg = b_ih[256 + t] + b_hh[256 + t];
      float bo = b_ih[384 + t] + b_hh[384 + t];
      float cc = sigmoidf_(bi) * tanhf(bg);
      h1l[t] = sigmoidf_(bo) * tanhf(cc);
    }
    __syncthreads();
    int j0 = (b - 64) * 128;
    if (t < 128) {
      int j = j0 + t;
      float acc = b_ih[j] + b_hh[j];
      #pragma unroll 8
      for (int d = 0; d < DD; ++d)
        acc = fmaf(W_ih[(j << 8) + d] + W_hh[(j << 7) + d], h1l[d], acc);
      gbase[j] = acc;
    }
  }
}

// ---------------------------------------------------------------------------
// k_fused: 512 blocks x 512 threads. Block bx owns molecules (bx, 1023-bx):
// waves 0-3 -> half 0, waves 4-7 -> half 1. y kept in registers across all
// three attention passes; per-block LSTM matvec (thread = gate row, both
// molecules share each weight read). No inter-block communication at all.
// ---------------------------------------------------------------------------
struct SMX {
  float ql[2][DD];        // current q per half
  float c1l[DD];          // c1 (bias-derived)
  float rp[2][4][DD];     // attn partial r
  float xcat[2][256];     // [h2 | r] per molecule for LSTM input
  float g2[2][512];       // gates
  float c2l[2][DD];       // c2
  float redm[2][4], reds[2][4], redf[2][4];
};

__global__ __launch_bounds__(512, 4) void k_fused(
    const float* __restrict__ y, const int* __restrict__ lengths,
    const float* __restrict__ Wfull, const float* __restrict__ gbase,
    const float* __restrict__ b_ih, const float* __restrict__ b_hh,
    const float* __restrict__ Wm, const float* __restrict__ bm,
    const float* __restrict__ mn, const float* __restrict__ sd,
    float* __restrict__ out) {
  __shared__ SMX s;
  const int t = threadIdx.x;
  const int lane = t & 63;
  const int h = t >> 8;                 // molecule half
  const int th = t & 255;
  const int w4 = (t >> 6) & 3;          // wave within half
  const int sub = lane & 15, g = lane >> 4;
  const int d0 = sub << 3;
  const int wbase = w4 << 2;
  const int m = h ? (1023 - (int)blockIdx.x) : (int)blockIdx.x;
  const int len = lengths[m];
  const float* yb = y + (size_t)m * (NN * DD);

  // ---- h1 (step-0 q) and c1 from biases ----
  if (th < DD) {
    float bi = b_ih[th] + b_hh[th];
    float bg = b_ih[256 + th] + b_hh[256 + th];
    float bo = b_ih[384 + th] + b_hh[384 + th];
    float cc = sigmoidf_(bi) * tanhf(bg);
    s.ql[h][th] = sigmoidf_(bo) * tanhf(cc);
    if (h == 0) s.c1l[th] = cc;
  }

  // ---- load y tile into registers (clamped rows; dups are cache hits) ----
  float4 va[8], vb[8];
  #pragma unroll
  for (int it = 0; it < 8; ++it) {
    int n = (it << 4) + wbase + g;
    int nc = (n < len) ? n : (len - 1);
    const float4* yr = (const float4*)(yb + nc * DD + d0);
    va[it] = yr[0];
    vb[it] = yr[1];
  }
  __syncthreads();

  // ---- attention from register-resident y ----
  auto attn = [&](float* rdst, bool is_final) {
    float4 q0 = *(const float4*)&s.ql[h][d0];
    float4 q1 = *(const float4*)&s.ql[h][d0 + 4];
    float ee[8];
    #pragma unroll
    for (int it = 0; it < 8; ++it) {
      int nw = (it << 4) + wbase;
      if (nw < len) {
        int n = nw + g;
        float p = fmaf(va[it].x, q0.x, fmaf(va[it].y, q0.y,
                  fmaf(va[it].z, q0.z, fmaf(va[it].w, q0.w,
                  fmaf(vb[it].x, q1.x, fmaf(vb[it].y, q1.y,
                  fmaf(vb[it].z, q1.z, vb[it].w * q1.w)))))));
        #pragma unroll
        for (int sh = 1; sh < 16; sh <<= 1) p += __shfl_xor(p, sh, 64);
        ee[it] = (n < len) ? p : -3.0e38f;
      } else {
        ee[it] = -3.0e38f;
      }
    }
    float mloc = ee[0];
    #pragma unroll
    for (int it = 1; it < 8; ++it) mloc = fmaxf(mloc, ee[it]);
    #pragma unroll
    for (int sh = 1; sh < 64; sh <<= 1) mloc = fmaxf(mloc, __shfl_xor(mloc, sh, 64));
    float a[8], sl = 0.0f;
    #pragma unroll
    for (int it = 0; it < 8; ++it) { a[it] = expf(ee[it] - mloc); sl += a[it]; }
    #pragma unroll
    for (int sh = 1; sh < 64; sh <<= 1) sl += __shfl_xor(sl, sh, 64);
    if (lane == 0) { s.redm[h][w4] = mloc; s.reds[h][w4] = sl; }
    __syncthreads();
    float m0_ = s.redm[h][0], m1_ = s.redm[h][1], m2_ = s.redm[h][2], m3_ = s.redm[h][3];
    float mx = fmaxf(fmaxf(m0_, m1_), fmaxf(m2_, m3_));
    float Zraw = s.reds[h][0] * expf(m0_ - mx) + s.reds[h][1] * expf(m1_ - mx) +
                 s.reds[h][2] * expf(m2_ - mx) + s.reds[h][3] * expf(m3_ - mx);
    float wscale = expf(mloc - mx) * (16.0f / Zraw);   // folds invZ + 16x dup

    float4 r0 = {0.f, 0.f, 0.f, 0.f}, r1 = {0.f, 0.f, 0.f, 0.f};
    #pragma unroll
    for (int it = 0; it < 8; ++it) {
      int nw = (it << 4) + wbase;
      if (nw < len) {
        float av = a[it];
        r0.x = fmaf(av, va[it].x, r0.x); r0.y = fmaf(av, va[it].y, r0.y);
        r0.z = fmaf(av, va[it].z, r0.z); r0.w = fmaf(av, va[it].w, r0.w);
        r1.x = fmaf(av, vb[it].x, r1.x); r1.y = fmaf(av, vb[it].y, r1.y);
        r1.z = fmaf(av, vb[it].z, r1.z); r1.w = fmaf(av, vb[it].w, r1.w);
      }
    }
    r0.x *= wscale; r0.y *= wscale; r0.z *= wscale; r0.w *= wscale;
    r1.x *= wscale; r1.y *= wscale; r1.z *= wscale; r1.w *= wscale;
    #pragma unroll
    for (int sh = 16; sh < 64; sh <<= 1) {
      r0.x += __shfl_xor(r0.x, sh, 64); r0.y += __shfl_xor(r0.y, sh, 64);
      r0.z += __shfl_xor(r0.z, sh, 64); r0.w += __shfl_xor(r0.w, sh, 64);
      r1.x += __shfl_xor(r1.x, sh, 64); r1.y += __shfl_xor(r1.y, sh, 64);
      r1.z += __shfl_xor(r1.z, sh, 64); r1.w += __shfl_xor(r1.w, sh, 64);
    }
    if (g == 0) {
      *(float4*)&s.rp[h][w4][d0] = r0;
      *(float4*)&s.rp[h][w4][d0 + 4] = r1;
    }
    __syncthreads();
    float r_ = 0.0f;
    if (th < DD) {
      r_ = s.rp[h][0][th] + s.rp[h][1][th] + s.rp[h][2][th] + s.rp[h][3][th];
      if (!is_final) rdst[th] = r_;
    }
    if (is_final) {
      float part = (th < DD) ? (Wm[th] * s.ql[h][th] + Wm[DD + th] * r_) : 0.0f;
      #pragma unroll
      for (int sh = 1; sh < 64; sh <<= 1) part += __shfl_xor(part, sh, 64);
      if (lane == 0) s.redf[h][w4] = part;
      __syncthreads();
      if (th == 0)
        out[m] = (s.redf[h][0] + s.redf[h][1] + s.redf[h][2] + s.redf[h][3] + bm[0])
                 * sd[0] + mn[0];
    } else {
      __syncthreads();                  // r visible in LDS for next phase
    }
  };

  // ============ step 0: attn(q=h1) -> r0 into xcat[*][128:] ============
  attn(&s.xcat[h][128], false);

  // ============ LSTM step 1: gates = gbase + Wr·r0 ============
  {
    int j = t;                          // gate row 0..511
    float bA = gbase[j];
    float aA0 = bA, aA1 = 0.f, aB0 = bA, aB1 = 0.f;
    const float4* wr = (const float4*)(Wfull + (j << 8) + 128);
    const float4* xA = (const float4*)&s.xcat[0][128];
    const float4* xB = (const float4*)&s.xcat[1][128];
    #pragma unroll 2
    for (int k = 0; k < 32; k += 2) {
      float4 w0 = wr[k], w1 = wr[k + 1];
      float4 a0 = xA[k], a1 = xA[k + 1];
      float4 b0 = xB[k], b1 = xB[k + 1];
      aA0 = fmaf(w0.x, a0.x, fmaf(w0.y, a0.y, fmaf(w0.z, a0.z, fmaf(w0.w, a0.w, aA0))));
      aA1 = fmaf(w1.x, a1.x, fmaf(w1.y, a1.y, fmaf(w1.z, a1.z, fmaf(w1.w, a1.w, aA1))));
      aB0 = fmaf(w0.x, b0.x, fmaf(w0.y, b0.y, fmaf(w0.z, b0.z, fmaf(w0.w, b0.w, aB0))));
      aB1 = fmaf(w1.x, b1.x, fmaf(w1.y, b1.y, fmaf(w1.z, b1.z, fmaf(w1.w, b1.w, aB1))));
    }
    s.g2[0][j] = aA0 + aA1;
    s.g2[1][j] = aB0 + aB1;
  }
  __syncthreads();
  if (t < 256) {
    int mol = t >> 7, u = t & 127;
    float I = s.g2[mol][u], F = s.g2[mol][128 + u];
    float G = s.g2[mol][256 + u], O = s.g2[mol][384 + u];
    float cc = fmaf(sigmoidf_(F), s.c1l[u], sigmoidf_(I) * tanhf(G));
    float hh = sigmoidf_(O) * tanhf(cc);
    s.c2l[mol][u] = cc;
    s.xcat[mol][u] = hh;
    s.ql[mol][u] = hh;
  }
  __syncthreads();

  // ============ step 1: attn(q=h2) -> r1 into xcat[*][128:] ============
  attn(&s.xcat[h][128], false);

  // ============ LSTM step 2: gates = bias + Wfull·[h2|r1] ============
  {
    int j = t;
    float bA = b_ih[j] + b_hh[j];
    float aA0 = bA, aA1 = 0.f, aB0 = bA, aB1 = 0.f;
    const float4* wr = (const float4*)(Wfull + (j << 8));
    const float4* xA = (const float4*)&s.xcat[0][0];
    const float4* xB = (const float4*)&s.xcat[1][0];
    #pragma unroll 2
    for (int k = 0; k < 64; k += 2) {
      float4 w0 = wr[k], w1 = wr[k + 1];
      float4 a0 = xA[k], a1 = xA[k + 1];
      float4 b0 = xB[k], b1 = xB[k + 1];
      aA0 = fmaf(w0.x, a0.x, fmaf(w0.y, a0.y, fmaf(w0.z, a0.z, fmaf(w0.w, a0.w, aA0))));
      aA1 = fmaf(w1.x, a1.x, fmaf(w1.y, a1.y, fmaf(w1.z, a1.z, fmaf(w1.w, a1.w, aA1))));
      aB0 = fmaf(w0.x, b0.x, fmaf(w0.y, b0.y, fmaf(w0.z, b0.z, fmaf(w0.w, b0.w, aB0))));
      aB1 = fmaf(w1.x, b1.x, fmaf(w1.y, b1.y, fmaf(w1.z, b1.z, fmaf(w1.w, b1.w, aB1))));
    }
    s.g2[0][j] = aA0 + aA1;
    s.g2[1][j] = aB0 + aB1;
  }
  __syncthreads();
  if (t < 256) {
    int mol = t >> 7, u = t & 127;
    float I = s.g2[mol][u], F = s.g2[mol][128 + u];
    float G = s.g2[mol][256 + u], O = s.g2[mol][384 + u];
    float cc = fmaf(sigmoidf_(F), s.c2l[mol][u], sigmoidf_(I) * tanhf(G));
    float hh = sigmoidf_(O) * tanhf(cc);
    s.ql[mol][u] = hh;
  }
  __syncthreads();

  // ============ step 2: attn(q=h3) + final projection ============
  attn(nullptr, true);
}

// ---------------------------------------------------------------------------
extern "C" void kernel_launch(void* const* d_in, const int* in_sizes, int n_in,
                              void* d_out, int out_size, void* d_ws, size_t ws_size,
                              hipStream_t stream) {
  const float* y    = (const float*)d_in[0];
  const int*   len  = (const int*)  d_in[1];
  const float* W_ih = (const float*)d_in[2];
  const float* W_hh = (const float*)d_in[3];
  const float* b_ih = (const float*)d_in[4];
  const float* b_hh = (const float*)d_in[5];
  const float* W_m  = (const float*)d_in[6];
  const float* b_m  = (const float*)d_in[7];
  const float* mean = (const float*)d_in[8];
  const float* sd   = (const float*)d_in[9];
  float* out = (float*)d_out;

  float* ws    = (float*)d_ws;
  float* Wfull = ws;                    // 512*256
  float* gbase = ws + 131072;           // 512

  k_prep2<<<68, 256, 0, stream>>>(W_ih, W_hh, b_ih, b_hh, Wfull, gbase);
  k_fused<<<512, 512, 0, stream>>>(y, len, Wfull, gbase, b_ih, b_hh,
                                   W_m, b_m, mean, sd, out);
}